// Round 2
// baseline (234.964 us; speedup 1.0000x reference)
//
#include <hip/hip_runtime.h>
#include <string.h>

// ---------------- problem constants ----------------
#define T_LEN   809
#define DD      304
#define EE      300
#define LQ      30
#define NCAND   12824      // candidates per batch
#define NPAD    12928      // 101 * 128 (padded rows per batch)
#define CIN     1212
#define H1      1024
#define H2      512
#define BATCH   4
#define MROWS_F (BATCH * NPAD)          // 51712 fused rows
#define KS      320                     // 304 padded to mult of 32 (scan-GEMM K)
#define TPAD    3328                    // 26 * 128

// mega-prep block ranges
#define MP_SCAN0   0          // 416 blocks  (208 virtual x 2 d-chunks)
#define MP_W1      416        // 3840 blocks (3072*320/256)
#define MP_W2      4256       // 2048 blocks (512*1024/256)
#define MP_BIAS2   6304       // 2 blocks
#define MP_BASE    6306       // 1024 blocks (4 b x 256 jg)
#define MP_TOTAL   7330

// alpha^(span+1), span in [0,16)
__device__ __constant__ float c_coef[16] = {
  0.9f, 0.81f, 0.729f, 0.6561f, 0.59049f, 0.531441f, 0.4782969f, 0.43046721f,
  0.387420489f, 0.3486784401f, 0.31381059609f, 0.282429536481f,
  0.2541865828329f, 0.22876792454961f, 0.205891132094649f, 0.1853020188851841f
};

__device__ __forceinline__ unsigned short f2bf(float f) {
  unsigned int u = __float_as_uint(f);
  u += 0x7fffu + ((u >> 16) & 1u);          // round-to-nearest-even
  return (unsigned short)(u >> 16);
}
__device__ __forceinline__ float bf2f(unsigned int h) {
  return __uint_as_float(h << 16);
}

typedef const __attribute__((address_space(1))) unsigned int GU32;
typedef __attribute__((address_space(3))) unsigned int LU32;
__device__ __forceinline__ void async16(const unsigned short* g, unsigned short* l) {
  __builtin_amdgcn_global_load_lds((GU32*)g, (LU32*)l, 16, 0, 0);
}

// ---------------- mega prep: scan + W1 split + W2 fold + bias2 + baseW ----------------
__global__ __launch_bounds__(256) void k_prep(const float* __restrict__ doc,
                                              const float* __restrict__ qe,
                                              const float* __restrict__ W1,
                                              const float* __restrict__ g1,
                                              const float* __restrict__ b1,
                                              const float* __restrict__ m1,
                                              const float* __restrict__ v1,
                                              const float* __restrict__ W2,
                                              const float* __restrict__ g2,
                                              const float* __restrict__ b2,
                                              const float* __restrict__ m2,
                                              const float* __restrict__ v2,
                                              unsigned short* __restrict__ Fz,
                                              unsigned short* __restrict__ Rz,
                                              unsigned short* __restrict__ Wlc,
                                              unsigned short* __restrict__ Wr,
                                              unsigned short* __restrict__ W2b,
                                              float* __restrict__ bias2,
                                              float* __restrict__ baseW)
{
  __shared__ float qs[EE];
  const int vb  = blockIdx.x;
  const int tid = threadIdx.x;

  if (vb < MP_W1) {
    // ---- scan section: vb in [0,416), 96-step lookback (alpha^96 ~ 4e-5) ----
    const int dchunk = vb & 1;
    const int rest   = vb >> 1;            // 0..207
    const int tchunk = rest % 26;
    const int b      = (rest / 26) & 3;
    const int dir    = rest / 104;
    const int d  = dchunk * 256 + tid;     // 0..511 (valid < 320)
    const int t0 = tchunk * 32;
    if (dir == 0) {
      if (tchunk == 0 && d < KS) Fz[((size_t)b * 810) * KS + d] = 0;   // zero row
      if (d >= DD) return;
      const float* db = doc + (size_t)b * T_LEN * DD + d;
      int start = t0 - 96; if (start < 0) start = 0;
      int end = t0 + 31; if (end > T_LEN - 1) end = T_LEN - 1;
      float s = 0.f;
      for (int t = start; t <= end; ++t) {
        s = fmaf(0.9f, s, db[(size_t)t * DD]);
        if (t >= t0) Fz[((size_t)b * 810 + 1 + t) * KS + d] = f2bf(s);
      }
    } else {
      if (tchunk == 0 && d < KS) Rz[((size_t)b * 810 + 809) * KS + d] = 0;  // zero row
      if (d >= DD) return;
      const float* db = doc + (size_t)b * T_LEN * DD + d;
      int t1 = t0 + 31; if (t1 > T_LEN - 1) t1 = T_LEN - 1;
      int start = t1 + 96; if (start > T_LEN - 1) start = T_LEN - 1;
      float s = 0.f;
      for (int t = start; t >= t0; --t) {
        s = fmaf(0.9f, s, db[(size_t)t * DD]);
        if (t <= t1) Rz[((size_t)b * 810 + t) * KS + d] = f2bf(s);
      }
    }
  } else if (vb < MP_W2) {
    // ---- W1 split: flat over 3072 x 320 ----
    const int e = (vb - MP_W1) * 256 + tid;
    const int j = e / KS;                  // 0..3071
    const int k = e - j * KS;              // 0..319
    int jj, koff; unsigned short* dst; size_t idx;
    if (j < 1024)      { jj = j;        koff = k;       dst = Wlc; idx = (size_t)j * KS + k; }
    else if (j < 2048) { jj = j - 1024; koff = 304 + k; dst = Wlc; idx = (size_t)j * KS + k; }
    else               { jj = j - 2048; koff = 608 + k; dst = Wr;  idx = (size_t)(j - 2048) * KS + k; }
    float w = 0.f;
    if (k < 304) w = W1[(size_t)jj * CIN + koff] * g1[jj] * rsqrtf(v1[jj] + 1e-5f);
    dst[idx] = f2bf(w);
  } else if (vb < MP_BIAS2) {
    // ---- W2 fold: flat over 512 x 1024 ----
    const int e = (vb - MP_W2) * 256 + tid;
    const int j = e >> 10;
    const int k = e & 1023;
    const float w = W2[(size_t)j * H1 + k] * g2[j] * rsqrtf(v2[j] + 1e-5f);
    W2b[(size_t)j * H1 + k] = f2bf(w);
  } else if (vb < MP_BASE) {
    // ---- bias2 ----
    const int i = (vb - MP_BIAS2) * 256 + tid;
    if (i < H2) {
      const float s = g2[i] * rsqrtf(v2[i] + 1e-5f);
      bias2[i] = b2[i] - m2[i] * s;
    }
  } else {
    // ---- baseW (2048-wide, cand half zero): 1024 blocks = (b, jg) ----
    const int flat = vb - MP_BASE;
    const int b  = flat >> 8;
    const int jg = flat & 255;
    const float* q = qe + (size_t)b * LQ * EE;
    for (int k = tid; k < EE; k += 256) {
      float s = 0.f;
      for (int t = 0; t < LQ; ++t) s = fmaf(s, 0.9f, q[(size_t)t * EE + k]);
      qs[k] = s;
    }
    __syncthreads();
    const int wv   = tid >> 6;
    const int lane = tid & 63;
    const int j = jg * 4 + wv;             // 0..1023
    const float* w = W1 + (size_t)j * CIN + 912;
    float acc = 0.f;
    for (int k = lane; k < EE; k += 64) acc = fmaf(qs[k], w[k], acc);
    #pragma unroll
    for (int off = 32; off; off >>= 1) acc += __shfl_down(acc, off);
    if (lane == 0) {
      const float sc = g1[j] * rsqrtf(v1[j] + 1e-5f);
      baseW[(size_t)b * 2048 + j]        = b1[j] - m1[j] * sc + acc * sc;
      baseW[(size_t)b * 2048 + 1024 + j] = 0.f;
    }
  }
}

// ---------------- GEMM machinery ----------------
typedef __attribute__((ext_vector_type(8))) short frag8;
typedef __attribute__((ext_vector_type(4))) float f32x4;

// 128x128 tile, BK=32, 4 waves of 64x64.  Chunk-swizzled LDS (conflict-free).
#define GEMM_KLOOP(A_, B_, K_)                                                   \
  __shared__ __align__(16) unsigned short As[128 * 32];                          \
  __shared__ __align__(16) unsigned short Bs[128 * 32];                          \
  const int tid  = threadIdx.x;                                                  \
  const int lane = tid & 63;                                                     \
  const int wv   = tid >> 6;                                                     \
  const int wm   = wv & 1, wn = wv >> 1;                                         \
  const int lr = lane >> 2;                                                      \
  const int lc = lane & 3;                                                       \
  const int sc = lc ^ ((lr >> 1) & 3);                                           \
  const unsigned short* gA = A_ + ((size_t)bm * 128 + wv * 32 + lr) * K_ + sc * 8; \
  const unsigned short* gB = B_ + ((size_t)bn * 128 + wv * 32 + lr) * K_ + sc * 8; \
  const size_t row16 = (size_t)16 * K_;                                          \
  unsigned short* lA0 = &As[wv * 1024];                                          \
  unsigned short* lB0 = &Bs[wv * 1024];                                          \
  f32x4 acc[4][4];                                                               \
  _Pragma("unroll")                                                              \
  for (int i = 0; i < 4; ++i)                                                    \
    _Pragma("unroll")                                                            \
    for (int j = 0; j < 4; ++j) acc[i][j] = (f32x4){0.f, 0.f, 0.f, 0.f};         \
  const int arow = lane & 15;                                                    \
  const int pg   = (lane >> 4) ^ ((arow >> 1) & 3);                              \
  const int aoff = (wm * 64 + arow) * 32 + pg * 8;                               \
  const int boff = (wn * 64 + arow) * 32 + pg * 8;                               \
  for (int kc = 0; kc < K_; kc += 32) {                                          \
    __syncthreads();                                                             \
    async16(gA + kc,         lA0);                                               \
    async16(gA + kc + row16, lA0 + 512);                                         \
    async16(gB + kc,         lB0);                                               \
    async16(gB + kc + row16, lB0 + 512);                                         \
    __syncthreads();                                                             \
    frag8 a[4], b[4];                                                            \
    _Pragma("unroll")                                                            \
    for (int i = 0; i < 4; ++i) a[i] = *(const frag8*)&As[aoff + i * 512];       \
    _Pragma("unroll")                                                            \
    for (int i = 0; i < 4; ++i) b[i] = *(const frag8*)&Bs[boff + i * 512];       \
    _Pragma("unroll")                                                            \
    for (int i = 0; i < 4; ++i)                                                  \
      _Pragma("unroll")                                                          \
      for (int j = 0; j < 4; ++j)                                                \
        acc[i][j] = __builtin_amdgcn_mfma_f32_16x16x32_bf16(a[i], b[j], acc[i][j], 0, 0, 0); \
  }

// ---------------- fused U-table GEMMs (UF and UR in one launch), bf16 out ----------------
__global__ __launch_bounds__(256, 4) void k_ugemm(const unsigned short* __restrict__ Fz,
                                                  const unsigned short* __restrict__ Wlc,
                                                  const unsigned short* __restrict__ Rz,
                                                  const unsigned short* __restrict__ Wr,
                                                  const float* __restrict__ baseW,
                                                  unsigned short* __restrict__ UF,
                                                  unsigned short* __restrict__ UR)
{
  int bx = blockIdx.x;
  const int isUF = (bx < 416);
  const unsigned short *Ap, *Bp; unsigned short* Cp; int bn, bm, Nout;
  if (isUF) { Ap = Fz; Bp = Wlc; Cp = UF; bn = bx & 15; bm = bx >> 4; Nout = 2048; }
  else { bx -= 416; Ap = Rz; Bp = Wr; Cp = UR; bn = bx & 7; bm = bx >> 3; Nout = 1024; }
  GEMM_KLOOP(Ap, Bp, KS)
  const int crow0 = bm * 128 + wm * 64 + ((lane >> 4) << 2);
  const int ccol0 = bn * 128 + wn * 64 + arow;
  #pragma unroll
  for (int i = 0; i < 4; ++i)
    #pragma unroll
    for (int j = 0; j < 4; ++j) {
      const int col = ccol0 + j * 16;
      #pragma unroll
      for (int r = 0; r < 4; ++r) {
        const int row = crow0 + i * 16 + r;
        float v = acc[i][j][r];
        if (isUF) {
          int bb = row / 810; if (bb > 3) bb = 3;   // clamp padded rows
          v += baseW[(size_t)bb * 2048 + col];
        }
        Cp[(size_t)row * Nout + col] = f2bf(v);
      }
    }
}

// ---------------- combine: h1 = relu(UL'[s] + UC[e+1] - coef*UC[s] + UR[e+1]) ----------------
__global__ __launch_bounds__(512) void k_combine(const unsigned short* __restrict__ UF,
                                                 const unsigned short* __restrict__ UR,
                                                 unsigned short* __restrict__ h1)
{
  __shared__ float s_ul[1024];
  __shared__ float s_ucs[1024];
  const int flat = (blockIdx.x & 7) * 405 + (blockIdx.x >> 3);
  if (flat >= BATCH * T_LEN) return;
  const int b = flat / T_LEN;
  const int s = flat - b * T_LEN;
  const int oct = threadIdx.x >> 6;      // 0..7: eight span-rows in flight
  const int t = threadIdx.x & 63;        // 16-elem slice
  const size_t rs = (size_t)b * 810 + s;
  const int e0 = t * 16;

  {
    const unsigned int u = *(const unsigned int*)(UF + rs * 2048 + threadIdx.x * 2);
    const unsigned int c = *(const unsigned int*)(UF + rs * 2048 + 1024 + threadIdx.x * 2);
    s_ul[threadIdx.x * 2]      = bf2f(u & 0xffff);
    s_ul[threadIdx.x * 2 + 1]  = bf2f(u >> 16);
    s_ucs[threadIdx.x * 2]     = bf2f(c & 0xffff);
    s_ucs[threadIdx.x * 2 + 1] = bf2f(c >> 16);
  }
  __syncthreads();

  float ul[16], ucs[16];
  #pragma unroll
  for (int k = 0; k < 4; ++k) {
    const float4 a = *(const float4*)&s_ul[e0 + k * 4];
    const float4 c = *(const float4*)&s_ucs[e0 + k * 4];
    ul[4*k] = a.x; ul[4*k+1] = a.y; ul[4*k+2] = a.z; ul[4*k+3] = a.w;
    ucs[4*k] = c.x; ucs[4*k+1] = c.y; ucs[4*k+2] = c.z; ucs[4*k+3] = c.w;
  }

  const int nspan = min(16, T_LEN - s);
  int r0;
  if (s < 794) r0 = s * 16;
  else { const int d = s - 794; r0 = 12704 + 15 * d - (d * (d - 1)) / 2; }

  #pragma unroll
  for (int sp = 0; sp < 16; sp += 8) {
    const int row = sp + oct;
    if (row < nspan) {
      const size_t re = rs + row + 1;
      const uint4 e0v = *(const uint4*)(UF + re * 2048 + 1024 + e0);
      const uint4 e1v = *(const uint4*)(UF + re * 2048 + 1024 + e0 + 8);
      const uint4 r0v = *(const uint4*)(UR + re * 1024 + e0);
      const uint4 r1v = *(const uint4*)(UR + re * 1024 + e0 + 8);
      const float c = c_coef[row];
      const unsigned int* pe0 = (const unsigned int*)&e0v;
      const unsigned int* pe1 = (const unsigned int*)&e1v;
      const unsigned int* pr0 = (const unsigned int*)&r0v;
      const unsigned int* pr1 = (const unsigned int*)&r1v;
      unsigned int o[8];
      #pragma unroll
      for (int i = 0; i < 4; ++i) {
        float xlo = ul[2*i]   + bf2f(pe0[i] & 0xffff) - c * ucs[2*i]   + bf2f(pr0[i] & 0xffff);
        float xhi = ul[2*i+1] + bf2f(pe0[i] >> 16)    - c * ucs[2*i+1] + bf2f(pr0[i] >> 16);
        xlo = xlo > 0.f ? xlo : 0.f;
        xhi = xhi > 0.f ? xhi : 0.f;
        o[i] = (unsigned int)f2bf(xlo) | ((unsigned int)f2bf(xhi) << 16);
        float ylo = ul[8+2*i]   + bf2f(pe1[i] & 0xffff) - c * ucs[8+2*i]   + bf2f(pr1[i] & 0xffff);
        float yhi = ul[8+2*i+1] + bf2f(pe1[i] >> 16)    - c * ucs[8+2*i+1] + bf2f(pr1[i] >> 16);
        ylo = ylo > 0.f ? ylo : 0.f;
        yhi = yhi > 0.f ? yhi : 0.f;
        o[4 + i] = (unsigned int)f2bf(ylo) | ((unsigned int)f2bf(yhi) << 16);
      }
      unsigned short* dst = h1 + ((size_t)b * NPAD + r0 + row) * H1 + e0;
      *(uint4*)dst = *(const uint4*)&o[0];
      *(uint4*)(dst + 8) = *(const uint4*)&o[4];
    }
  }
}

// =====================================================================
// GEMM2: 256x256 tile, BK=64, 8 waves, 8-phase counted-vmcnt schedule
// (m201 template: T2 swizzle + T3/T4 counted vmcnt + T5 setprio)
// A = h1 [51712][1024] bf16, B = W2b [512][1024] bf16 (B rows = C cols).
// Fused epilogue: bias+relu+W3 -> 2 partials/row into P (stride 4).
//
// LDS (128 KiB): buf q in {0,1}: A-half h: q*64K + h*16K; B-half h: +32K.
// Each half = 2 k-blocks [128 rows][32 shorts] (8 KiB each).  Swizzle:
// within a k-block, byte col ^= ((row&8)<<2).  global_load_lds dest is
// linear; the *source* address is pre-swizzled (rule #21).
//
// R1 fix: stage schedule shifted so every stage targets a slot whose last
// read was in a STRICTLY earlier phase (barrier-ordered; R0 had 5
// same-phase stage/read races per iter -> absmax 6.78).  Ledger:
// prologue 6 half-tiles + vmcnt(4); steady-state vmcnt(4) at ph4/ph8
// lands exactly the 4 halves read by the next 4 phases.
// =====================================================================
#define NT_K   16      // 1024 / 64 K-tiles
#define NITER  8       // 2 K-tiles per iteration

__global__ __launch_bounds__(512, 2) void k_gemm2x(const unsigned short* __restrict__ A,
                                                   const unsigned short* __restrict__ B,
                                                   const float* __restrict__ bias,
                                                   const float* __restrict__ W3,
                                                   float* __restrict__ P)
{
  __shared__ __align__(16) unsigned short L[65536];   // 128 KiB

  // bijective XCD swizzle (m204): nwg=404, q=50, r=4
  const int orig = blockIdx.x;
  const int xcd = orig & 7, cidx = orig >> 3;
  const int wg = (xcd < 4 ? xcd * 51 : 204 + (xcd - 4) * 50) + cidx;
  const int bm = wg >> 1, bn = wg & 1;   // bn fastest: (bm,0),(bm,1) same XCD

  const int tid  = threadIdx.x;
  const int w    = tid >> 6;
  const int lane = tid & 63;
  const int wr = w >> 2, wc = w & 3;     // 2 x 4 wave grid per quadrant
  const int arow = lane & 15;
  // swizzled col offset (shorts): colbyte (lane>>4)*16, byte bit5 ^= row bit3
  const int acol_sh = ((((lane >> 4) << 4) ^ ((arow & 8) << 2)) >> 1);

  // ---- staging source mapping (per-thread, pre-swizzled) ----
  // chunk c = tid covers LDS bytes c*16..+16 of an 8 KiB k-block;
  // source chunk c' = c ^ ((c>>5 & 1)<<1)  (same involution both sides)
  const int cs   = tid ^ (((tid >> 5) & 1) << 1);
  const size_t srcOff = ((size_t)(cs >> 2) << 10) + (size_t)((cs & 3) << 3); // row*1024 + col8*8
  const unsigned short* Ab = A + ((size_t)bm << 18) + srcOff;  // bm*256*1024
  const unsigned short* Bb = B + ((size_t)bn << 18) + srcOff;
  unsigned short* ldsw = &L[w * 512];    // wave-uniform stage base (shorts)

  // ---- ds_read per-lane bases (short units, within a buffer) ----
  const int aBase = (wr * 64 + arow) * 32 + acol_sh;           // A-half local
  const int bBase = 16384 + (wc * 32 + arow) * 32 + acol_sh;   // B region +32KiB

  f32x4 acc[2][2][4][2];
  #pragma unroll
  for (int qm = 0; qm < 2; ++qm)
    #pragma unroll
    for (int qn = 0; qn < 2; ++qn)
      #pragma unroll
      for (int i = 0; i < 4; ++i)
        #pragma unroll
        for (int j = 0; j < 2; ++j) acc[qm][qn][i][j] = (f32x4){0.f, 0.f, 0.f, 0.f};

// STAGE(buf, isB, half, kt): one half-tile = 2 k-blocks = 2 global_load_lds x16B
#define STAGE(buf_, isB_, half_, kt_)                                                 \
  {                                                                                   \
    const unsigned short* s_ = (isB_ ? Bb : Ab) + (size_t)(half_) * 131072 + (kt_) * 64; \
    unsigned short* d_ = ldsw + (buf_) * 32768 + (isB_) * 16384 + (half_) * 8192;     \
    async16(s_,      d_);                                                             \
    async16(s_ + 32, d_ + 4096);                                                      \
  }

// one phase: 12 ds_read_b128 + stage + barrier + lgkmcnt(0) + 16 MFMA + barrier
#define PHASE(q_, qm_, qn_, VMW_, ...)                                                \
  {                                                                                   \
    frag8 af[4][2], bf[2][2];                                                         \
    _Pragma("unroll")                                                                 \
    for (int ks = 0; ks < 2; ++ks) {                                                  \
      _Pragma("unroll")                                                               \
      for (int i = 0; i < 4; ++i)                                                     \
        af[i][ks] = *(const frag8*)&L[(q_)*32768 + (qm_)*8192 + ks*4096 + i*512 + aBase]; \
      _Pragma("unroll")                                                               \
      for (int j = 0; j < 2; ++j)                                                     \
        bf[j][ks] = *(const frag8*)&L[(q_)*32768 + (qn_)*8192 + ks*4096 + j*512 + bBase]; \
    }                                                                                 \
    __VA_ARGS__                                                                       \
    __builtin_amdgcn_sched_barrier(0);                                                \
    __builtin_amdgcn_s_barrier();                                                     \
    asm volatile("s_waitcnt lgkmcnt(0)" ::: "memory");                                \
    __builtin_amdgcn_sched_barrier(0);                                                \
    __builtin_amdgcn_s_setprio(1);                                                    \
    _Pragma("unroll")                                                                 \
    for (int ks = 0; ks < 2; ++ks)                                                    \
      _Pragma("unroll")                                                               \
      for (int i = 0; i < 4; ++i)                                                     \
        _Pragma("unroll")                                                             \
        for (int j = 0; j < 2; ++j)                                                   \
          acc[qm_][qn_][i][j] = __builtin_amdgcn_mfma_f32_16x16x32_bf16(              \
              af[i][ks], bf[j][ks], acc[qm_][qn_][i][j], 0, 0, 0);                    \
    __builtin_amdgcn_s_setprio(0);                                                    \
    VMW_;                                                                             \
    __builtin_amdgcn_s_barrier();                                                     \
    __builtin_amdgcn_sched_barrier(0);                                                \
  }

#define VM_PF()                                                                       \
  { if (pf) asm volatile("s_waitcnt vmcnt(4)" ::: "memory");                          \
    else    asm volatile("s_waitcnt vmcnt(0)" ::: "memory"); }
#define VM_NONE()

  // ---- prologue: tile0 all 4 halves + tile1 {A0,B0} = 12 loads ----
  STAGE(0, 0, 0, 0);   // A0(t0)
  STAGE(0, 1, 0, 0);   // B0(t0)
  STAGE(0, 0, 1, 0);   // A1(t0)
  STAGE(0, 1, 1, 0);   // B1(t0)
  STAGE(1, 0, 0, 1);   // A0(t1)
  STAGE(1, 1, 0, 1);   // B0(t1)
  asm volatile("s_waitcnt vmcnt(4)" ::: "memory");   // tile0 fully landed
  __builtin_amdgcn_s_barrier();
  __builtin_amdgcn_sched_barrier(0);

  // ---- main loop: 8 iterations x 2 K-tiles ----
  // reads: ph1{0.A0,0.B0} ph2{0.A0,0.B1} ph3{0.A1,0.B0} ph4{0.A1,0.B1}
  //        ph5{1.A0,1.B0} ph6{1.A0,1.B1} ph7{1.A1,1.B0} ph8{1.A1,1.B1}
  // slot deaths: 0.A0@2 0.B0@3 0.A1@4 0.B1@4 1.A0@6 1.B0@7 1.A1@8 1.B1@8
  // each stage targets a slot dead since a strictly earlier phase:
  for (int it = 0; it < NITER; ++it) {
    const int t = it * 2;
    const bool pf = (it < NITER - 1);
    PHASE(0, 0, 0, VM_NONE(), STAGE(1, 0, 1, t + 1);)               // ph1: buf1.A1 <- t+1
    PHASE(0, 0, 1, VM_NONE(), STAGE(1, 1, 1, t + 1);)               // ph2: buf1.B1 <- t+1
    PHASE(0, 1, 0, VM_NONE(), if (pf) STAGE(0, 0, 0, t + 2);)       // ph3: buf0.A0 <- t+2
    PHASE(0, 1, 1, VM_PF(),   if (pf) STAGE(0, 1, 0, t + 2);)       // ph4: buf0.B0 <- t+2 + vmcnt
    PHASE(1, 0, 0, VM_NONE(), if (pf) STAGE(0, 0, 1, t + 2);)       // ph5: buf0.A1 <- t+2
    PHASE(1, 0, 1, VM_NONE(), if (pf) STAGE(0, 1, 1, t + 2);)       // ph6: buf0.B1 <- t+2
    PHASE(1, 1, 0, VM_NONE(), if (pf) STAGE(1, 0, 0, t + 3);)       // ph7: buf1.A0 <- t+3
    PHASE(1, 1, 1, VM_PF(),   if (pf) STAGE(1, 1, 0, t + 3);)       // ph8: buf1.B0 <- t+3 + vmcnt
  }

  // ---- fused epilogue: bias + relu + W3 -> per-row partials over 256 cols ----
  __syncthreads();                       // fence before overlaying red on L
  float* redf = (float*)L;               // red[row_local 0..255][wc 0..3][2]

  float bj[2][2], w0v[2][2], w1v[2][2];
  #pragma unroll
  for (int qn = 0; qn < 2; ++qn)
    #pragma unroll
    for (int j = 0; j < 2; ++j) {
      const int col = bn * 256 + qn * 128 + wc * 32 + j * 16 + arow;
      bj[qn][j]  = bias[col];
      w0v[qn][j] = W3[col];
      w1v[qn][j] = W3[H2 + col];
    }
  const int g = lane >> 4;
  #pragma unroll
  for (int qm = 0; qm < 2; ++qm)
    #pragma unroll
    for (int i = 0; i < 4; ++i)
      #pragma unroll
      for (int r = 0; r < 4; ++r) {
        float s0 = 0.f, s1 = 0.f;
        #pragma unroll
        for (int qn = 0; qn < 2; ++qn)
          #pragma unroll
          for (int j = 0; j < 2; ++j) {
            float v = acc[qm][qn][i][j][r] + bj[qn][j];
            v = v > 0.f ? v : 0.f;
            s0 = fmaf(v, w0v[qn][j], s0);
            s1 = fmaf(v, w1v[qn][j], s1);
          }
        #pragma unroll
        for (int m = 1; m < 16; m <<= 1) { s0 += __shfl_xor(s0, m); s1 += __shfl_xor(s1, m); }
        if (arow == 0) {
          const int rl = qm * 128 + wr * 64 + i * 16 + g * 4 + r;
          redf[(rl * 4 + wc) * 2]     = s0;
          redf[(rl * 4 + wc) * 2 + 1] = s1;
        }
      }
  __syncthreads();
  {
    const int rl = tid >> 1, s = tid & 1;
    const float v = redf[(rl * 4 + 0) * 2 + s] + redf[(rl * 4 + 1) * 2 + s]
                  + redf[(rl * 4 + 2) * 2 + s] + redf[(rl * 4 + 3) * 2 + s];
    P[((size_t)(bm * 256 + rl)) * 4 + bn * 2 + s] = v;
  }
#undef STAGE
#undef PHASE
#undef VM_PF
#undef VM_NONE
}

// ---------------- final: sum 2 bn-partials per row -> out ----------------
__global__ __launch_bounds__(256) void k_fin(const float* __restrict__ P, float* __restrict__ out)
{
  const int row = blockIdx.x * 256 + threadIdx.x;
  if (row >= MROWS_F) return;
  const int b = row / NPAD;
  const int rr = row - b * NPAD;
  if (rr >= NCAND) return;
  const float4 pa = ((const float4*)P)[row];
  float* o = out + ((size_t)b * NCAND + rr) * 2;
  o[0] = pa.x + pa.z;
  o[1] = pa.y + pa.w;
}

// ---------------- launch ----------------
extern "C" void kernel_launch(void* const* d_in, const int* in_sizes, int n_in,
                              void* d_out, int out_size, void* d_ws, size_t ws_size,
                              hipStream_t stream)
{
  const float* doc = (const float*)d_in[0];
  const float* qe  = (const float*)d_in[1];
  const float* W1  = (const float*)d_in[2];
  const float* g1  = (const float*)d_in[3];
  const float* b1  = (const float*)d_in[4];
  const float* m1  = (const float*)d_in[5];
  const float* v1  = (const float*)d_in[6];
  const float* W2  = (const float*)d_in[7];
  const float* g2  = (const float*)d_in[8];
  const float* b2  = (const float*)d_in[9];
  const float* m2  = (const float*)d_in[10];
  const float* v2  = (const float*)d_in[11];
  const float* W3  = (const float*)d_in[12];
  float* out = (float*)d_out;

  char* ws = (char*)d_ws;
  size_t off = 0;
  auto alloc = [&](size_t bytes) -> void* {
    void* p = ws + off;
    off = (off + bytes + 255) & ~(size_t)255;
    return p;
  };
  unsigned short* Fz    = (unsigned short*)alloc((size_t)TPAD * KS * 2);
  unsigned short* Rz    = (unsigned short*)alloc((size_t)TPAD * KS * 2);
  unsigned short* Wlc   = (unsigned short*)alloc((size_t)2048 * KS * 2);
  unsigned short* Wr    = (unsigned short*)alloc((size_t)1024 * KS * 2);
  unsigned short* W2b   = (unsigned short*)alloc((size_t)H2 * H1 * 2);
  float*          bias2 = (float*)alloc((size_t)H2 * 4);
  float*          baseW = (float*)alloc((size_t)BATCH * 2048 * 4);
  unsigned short* UF    = (unsigned short*)alloc((size_t)TPAD * 2048 * 2);
  unsigned short* UR    = (unsigned short*)alloc((size_t)TPAD * 1024 * 2);
  unsigned short* h1    = (unsigned short*)alloc((size_t)MROWS_F * H1 * 2);
  float*          P     = (float*)alloc((size_t)MROWS_F * 4 * 4);
  (void)ws_size;

  // 1. fused prep (scan + qf/baseW + weight folds)
  k_prep<<<dim3(MP_TOTAL), 256, 0, stream>>>(doc, qe, W1, g1, b1, m1, v1,
                                             W2, g2, b2, m2, v2,
                                             Fz, Rz, Wlc, Wr, W2b, bias2, baseW);
  // 2. fused U-table GEMMs (base folded into UF)
  k_ugemm<<<dim3(416 + 208), 256, 0, stream>>>(Fz, Wlc, Rz, Wr, baseW, UF, UR);
  // 3. gather-combine -> h1 (bf16)
  k_combine<<<dim3(8 * 405), 512, 0, stream>>>(UF, UR, h1);
  // 4. GEMM2: 256^2 8-phase counted-vmcnt template, fused W3 partials
  k_gemm2x<<<dim3(404), 512, 0, stream>>>(h1, W2b, bias2, W3, P);
  // 5. reduce partials -> out
  k_fin<<<dim3((MROWS_F + 255) / 256), 256, 0, stream>>>(P, out);
}

// Round 3
// 226.767 us; speedup vs baseline: 1.0361x; 1.0361x over previous
//
#include <hip/hip_runtime.h>
#include <string.h>

// ---------------- problem constants ----------------
#define T_LEN   809
#define DD      304
#define EE      300
#define LQ      30
#define NCAND   12824      // candidates per batch
#define NPAD    12928      // 101 * 128 (padded rows per batch)
#define CIN     1212
#define H1      1024
#define H2      512
#define BATCH   4
#define MROWS_F (BATCH * NPAD)          // 51712 fused rows
#define KS      320                     // 304 padded to mult of 32 (scan-GEMM K)
#define TPAD    3328                    // 26 * 128

// mega-prep block ranges
#define MP_SCAN0   0          // 416 blocks  (208 virtual x 2 d-chunks)
#define MP_W1      416        // 3840 blocks (3072*320/256)
#define MP_W2      4256       // 2048 blocks (512*1024/256)
#define MP_BIAS2   6304       // 2 blocks
#define MP_BASE    6306       // 1024 blocks (4 b x 256 jg)
#define MP_TOTAL   7330

// alpha^(span+1), span in [0,16)
__device__ __constant__ float c_coef[16] = {
  0.9f, 0.81f, 0.729f, 0.6561f, 0.59049f, 0.531441f, 0.4782969f, 0.43046721f,
  0.387420489f, 0.3486784401f, 0.31381059609f, 0.282429536481f,
  0.2541865828329f, 0.22876792454961f, 0.205891132094649f, 0.1853020188851841f
};

__device__ __forceinline__ unsigned short f2bf(float f) {
  unsigned int u = __float_as_uint(f);
  u += 0x7fffu + ((u >> 16) & 1u);          // round-to-nearest-even
  return (unsigned short)(u >> 16);
}
__device__ __forceinline__ float bf2f(unsigned int h) {
  return __uint_as_float(h << 16);
}

typedef const __attribute__((address_space(1))) unsigned int GU32;
typedef __attribute__((address_space(3))) unsigned int LU32;
__device__ __forceinline__ void async16(const unsigned short* g, unsigned short* l) {
  __builtin_amdgcn_global_load_lds((GU32*)g, (LU32*)l, 16, 0, 0);
}

// ---------------- mega prep: scan + W1 split + W2 fold + bias2 + baseW ----------------
__global__ __launch_bounds__(256) void k_prep(const float* __restrict__ doc,
                                              const float* __restrict__ qe,
                                              const float* __restrict__ W1,
                                              const float* __restrict__ g1,
                                              const float* __restrict__ b1,
                                              const float* __restrict__ m1,
                                              const float* __restrict__ v1,
                                              const float* __restrict__ W2,
                                              const float* __restrict__ g2,
                                              const float* __restrict__ b2,
                                              const float* __restrict__ m2,
                                              const float* __restrict__ v2,
                                              unsigned short* __restrict__ Fz,
                                              unsigned short* __restrict__ Rz,
                                              unsigned short* __restrict__ Wlc,
                                              unsigned short* __restrict__ Wr,
                                              unsigned short* __restrict__ W2b,
                                              float* __restrict__ bias2,
                                              float* __restrict__ baseW)
{
  __shared__ float qs[EE];
  const int vb  = blockIdx.x;
  const int tid = threadIdx.x;

  if (vb < MP_W1) {
    // ---- scan section: vb in [0,416), 96-step lookback (alpha^96 ~ 4e-5) ----
    const int dchunk = vb & 1;
    const int rest   = vb >> 1;            // 0..207
    const int tchunk = rest % 26;
    const int b      = (rest / 26) & 3;
    const int dir    = rest / 104;
    const int d  = dchunk * 256 + tid;     // 0..511 (valid < 320)
    const int t0 = tchunk * 32;
    if (dir == 0) {
      if (tchunk == 0 && d < KS) Fz[((size_t)b * 810) * KS + d] = 0;   // zero row
      if (d >= DD) return;
      const float* db = doc + (size_t)b * T_LEN * DD + d;
      int start = t0 - 96; if (start < 0) start = 0;
      int end = t0 + 31; if (end > T_LEN - 1) end = T_LEN - 1;
      float s = 0.f;
      for (int t = start; t <= end; ++t) {
        s = fmaf(0.9f, s, db[(size_t)t * DD]);
        if (t >= t0) Fz[((size_t)b * 810 + 1 + t) * KS + d] = f2bf(s);
      }
    } else {
      if (tchunk == 0 && d < KS) Rz[((size_t)b * 810 + 809) * KS + d] = 0;  // zero row
      if (d >= DD) return;
      const float* db = doc + (size_t)b * T_LEN * DD + d;
      int t1 = t0 + 31; if (t1 > T_LEN - 1) t1 = T_LEN - 1;
      int start = t1 + 96; if (start > T_LEN - 1) start = T_LEN - 1;
      float s = 0.f;
      for (int t = start; t >= t0; --t) {
        s = fmaf(0.9f, s, db[(size_t)t * DD]);
        if (t <= t1) Rz[((size_t)b * 810 + t) * KS + d] = f2bf(s);
      }
    }
  } else if (vb < MP_W2) {
    // ---- W1 split: flat over 3072 x 320 ----
    const int e = (vb - MP_W1) * 256 + tid;
    const int j = e / KS;                  // 0..3071
    const int k = e - j * KS;              // 0..319
    int jj, koff; unsigned short* dst; size_t idx;
    if (j < 1024)      { jj = j;        koff = k;       dst = Wlc; idx = (size_t)j * KS + k; }
    else if (j < 2048) { jj = j - 1024; koff = 304 + k; dst = Wlc; idx = (size_t)j * KS + k; }
    else               { jj = j - 2048; koff = 608 + k; dst = Wr;  idx = (size_t)(j - 2048) * KS + k; }
    float w = 0.f;
    if (k < 304) w = W1[(size_t)jj * CIN + koff] * g1[jj] * rsqrtf(v1[jj] + 1e-5f);
    dst[idx] = f2bf(w);
  } else if (vb < MP_BIAS2) {
    // ---- W2 fold: flat over 512 x 1024 ----
    const int e = (vb - MP_W2) * 256 + tid;
    const int j = e >> 10;
    const int k = e & 1023;
    const float w = W2[(size_t)j * H1 + k] * g2[j] * rsqrtf(v2[j] + 1e-5f);
    W2b[(size_t)j * H1 + k] = f2bf(w);
  } else if (vb < MP_BASE) {
    // ---- bias2 ----
    const int i = (vb - MP_BIAS2) * 256 + tid;
    if (i < H2) {
      const float s = g2[i] * rsqrtf(v2[i] + 1e-5f);
      bias2[i] = b2[i] - m2[i] * s;
    }
  } else {
    // ---- baseW (2048-wide, cand half zero): 1024 blocks = (b, jg) ----
    const int flat = vb - MP_BASE;
    const int b  = flat >> 8;
    const int jg = flat & 255;
    const float* q = qe + (size_t)b * LQ * EE;
    for (int k = tid; k < EE; k += 256) {
      float s = 0.f;
      for (int t = 0; t < LQ; ++t) s = fmaf(s, 0.9f, q[(size_t)t * EE + k]);
      qs[k] = s;
    }
    __syncthreads();
    const int wv   = tid >> 6;
    const int lane = tid & 63;
    const int j = jg * 4 + wv;             // 0..1023
    const float* w = W1 + (size_t)j * CIN + 912;
    float acc = 0.f;
    for (int k = lane; k < EE; k += 64) acc = fmaf(qs[k], w[k], acc);
    #pragma unroll
    for (int off = 32; off; off >>= 1) acc += __shfl_down(acc, off);
    if (lane == 0) {
      const float sc = g1[j] * rsqrtf(v1[j] + 1e-5f);
      baseW[(size_t)b * 2048 + j]        = b1[j] - m1[j] * sc + acc * sc;
      baseW[(size_t)b * 2048 + 1024 + j] = 0.f;
    }
  }
}

// ---------------- GEMM machinery ----------------
typedef __attribute__((ext_vector_type(8))) short frag8;
typedef __attribute__((ext_vector_type(4))) float f32x4;

// 128x128 tile, BK=32, 4 waves of 64x64.  Chunk-swizzled LDS (conflict-free).
#define GEMM_KLOOP(A_, B_, K_)                                                   \
  __shared__ __align__(16) unsigned short As[128 * 32];                          \
  __shared__ __align__(16) unsigned short Bs[128 * 32];                          \
  const int tid  = threadIdx.x;                                                  \
  const int lane = tid & 63;                                                     \
  const int wv   = tid >> 6;                                                     \
  const int wm   = wv & 1, wn = wv >> 1;                                         \
  const int lr = lane >> 2;                                                      \
  const int lc = lane & 3;                                                       \
  const int sc = lc ^ ((lr >> 1) & 3);                                           \
  const unsigned short* gA = A_ + ((size_t)bm * 128 + wv * 32 + lr) * K_ + sc * 8; \
  const unsigned short* gB = B_ + ((size_t)bn * 128 + wv * 32 + lr) * K_ + sc * 8; \
  const size_t row16 = (size_t)16 * K_;                                          \
  unsigned short* lA0 = &As[wv * 1024];                                          \
  unsigned short* lB0 = &Bs[wv * 1024];                                          \
  f32x4 acc[4][4];                                                               \
  _Pragma("unroll")                                                              \
  for (int i = 0; i < 4; ++i)                                                    \
    _Pragma("unroll")                                                            \
    for (int j = 0; j < 4; ++j) acc[i][j] = (f32x4){0.f, 0.f, 0.f, 0.f};         \
  const int arow = lane & 15;                                                    \
  const int pg   = (lane >> 4) ^ ((arow >> 1) & 3);                              \
  const int aoff = (wm * 64 + arow) * 32 + pg * 8;                               \
  const int boff = (wn * 64 + arow) * 32 + pg * 8;                               \
  for (int kc = 0; kc < K_; kc += 32) {                                          \
    __syncthreads();                                                             \
    async16(gA + kc,         lA0);                                               \
    async16(gA + kc + row16, lA0 + 512);                                         \
    async16(gB + kc,         lB0);                                               \
    async16(gB + kc + row16, lB0 + 512);                                         \
    __syncthreads();                                                             \
    frag8 a[4], b[4];                                                            \
    _Pragma("unroll")                                                            \
    for (int i = 0; i < 4; ++i) a[i] = *(const frag8*)&As[aoff + i * 512];       \
    _Pragma("unroll")                                                            \
    for (int i = 0; i < 4; ++i) b[i] = *(const frag8*)&Bs[boff + i * 512];       \
    _Pragma("unroll")                                                            \
    for (int i = 0; i < 4; ++i)                                                  \
      _Pragma("unroll")                                                          \
      for (int j = 0; j < 4; ++j)                                                \
        acc[i][j] = __builtin_amdgcn_mfma_f32_16x16x32_bf16(a[i], b[j], acc[i][j], 0, 0, 0); \
  }

// ---------------- fused U-table GEMMs (UF and UR in one launch), bf16 out ----------------
__global__ __launch_bounds__(256, 4) void k_ugemm(const unsigned short* __restrict__ Fz,
                                                  const unsigned short* __restrict__ Wlc,
                                                  const unsigned short* __restrict__ Rz,
                                                  const unsigned short* __restrict__ Wr,
                                                  const float* __restrict__ baseW,
                                                  unsigned short* __restrict__ UF,
                                                  unsigned short* __restrict__ UR)
{
  int bx = blockIdx.x;
  const int isUF = (bx < 416);
  const unsigned short *Ap, *Bp; unsigned short* Cp; int bn, bm, Nout;
  if (isUF) { Ap = Fz; Bp = Wlc; Cp = UF; bn = bx & 15; bm = bx >> 4; Nout = 2048; }
  else { bx -= 416; Ap = Rz; Bp = Wr; Cp = UR; bn = bx & 7; bm = bx >> 3; Nout = 1024; }
  GEMM_KLOOP(Ap, Bp, KS)
  const int crow0 = bm * 128 + wm * 64 + ((lane >> 4) << 2);
  const int ccol0 = bn * 128 + wn * 64 + arow;
  #pragma unroll
  for (int i = 0; i < 4; ++i)
    #pragma unroll
    for (int j = 0; j < 4; ++j) {
      const int col = ccol0 + j * 16;
      #pragma unroll
      for (int r = 0; r < 4; ++r) {
        const int row = crow0 + i * 16 + r;
        float v = acc[i][j][r];
        if (isUF) {
          int bb = row / 810; if (bb > 3) bb = 3;   // clamp padded rows
          v += baseW[(size_t)bb * 2048 + col];
        }
        Cp[(size_t)row * Nout + col] = f2bf(v);
      }
    }
}

// ---------------- combine: h1 = relu(UL'[s] + UC[e+1] - coef*UC[s] + UR[e+1]) ----------------
__global__ __launch_bounds__(512) void k_combine(const unsigned short* __restrict__ UF,
                                                 const unsigned short* __restrict__ UR,
                                                 unsigned short* __restrict__ h1)
{
  __shared__ float s_ul[1024];
  __shared__ float s_ucs[1024];
  const int flat = (blockIdx.x & 7) * 405 + (blockIdx.x >> 3);
  if (flat >= BATCH * T_LEN) return;
  const int b = flat / T_LEN;
  const int s = flat - b * T_LEN;
  const int oct = threadIdx.x >> 6;      // 0..7: eight span-rows in flight
  const int t = threadIdx.x & 63;        // 16-elem slice
  const size_t rs = (size_t)b * 810 + s;
  const int e0 = t * 16;

  {
    const unsigned int u = *(const unsigned int*)(UF + rs * 2048 + threadIdx.x * 2);
    const unsigned int c = *(const unsigned int*)(UF + rs * 2048 + 1024 + threadIdx.x * 2);
    s_ul[threadIdx.x * 2]      = bf2f(u & 0xffff);
    s_ul[threadIdx.x * 2 + 1]  = bf2f(u >> 16);
    s_ucs[threadIdx.x * 2]     = bf2f(c & 0xffff);
    s_ucs[threadIdx.x * 2 + 1] = bf2f(c >> 16);
  }
  __syncthreads();

  float ul[16], ucs[16];
  #pragma unroll
  for (int k = 0; k < 4; ++k) {
    const float4 a = *(const float4*)&s_ul[e0 + k * 4];
    const float4 c = *(const float4*)&s_ucs[e0 + k * 4];
    ul[4*k] = a.x; ul[4*k+1] = a.y; ul[4*k+2] = a.z; ul[4*k+3] = a.w;
    ucs[4*k] = c.x; ucs[4*k+1] = c.y; ucs[4*k+2] = c.z; ucs[4*k+3] = c.w;
  }

  const int nspan = min(16, T_LEN - s);
  int r0;
  if (s < 794) r0 = s * 16;
  else { const int d = s - 794; r0 = 12704 + 15 * d - (d * (d - 1)) / 2; }

  #pragma unroll
  for (int sp = 0; sp < 16; sp += 8) {
    const int row = sp + oct;
    if (row < nspan) {
      const size_t re = rs + row + 1;
      const uint4 e0v = *(const uint4*)(UF + re * 2048 + 1024 + e0);
      const uint4 e1v = *(const uint4*)(UF + re * 2048 + 1024 + e0 + 8);
      const uint4 r0v = *(const uint4*)(UR + re * 1024 + e0);
      const uint4 r1v = *(const uint4*)(UR + re * 1024 + e0 + 8);
      const float c = c_coef[row];
      const unsigned int* pe0 = (const unsigned int*)&e0v;
      const unsigned int* pe1 = (const unsigned int*)&e1v;
      const unsigned int* pr0 = (const unsigned int*)&r0v;
      const unsigned int* pr1 = (const unsigned int*)&r1v;
      unsigned int o[8];
      #pragma unroll
      for (int i = 0; i < 4; ++i) {
        float xlo = ul[2*i]   + bf2f(pe0[i] & 0xffff) - c * ucs[2*i]   + bf2f(pr0[i] & 0xffff);
        float xhi = ul[2*i+1] + bf2f(pe0[i] >> 16)    - c * ucs[2*i+1] + bf2f(pr0[i] >> 16);
        xlo = xlo > 0.f ? xlo : 0.f;
        xhi = xhi > 0.f ? xhi : 0.f;
        o[i] = (unsigned int)f2bf(xlo) | ((unsigned int)f2bf(xhi) << 16);
        float ylo = ul[8+2*i]   + bf2f(pe1[i] & 0xffff) - c * ucs[8+2*i]   + bf2f(pr1[i] & 0xffff);
        float yhi = ul[8+2*i+1] + bf2f(pe1[i] >> 16)    - c * ucs[8+2*i+1] + bf2f(pr1[i] >> 16);
        ylo = ylo > 0.f ? ylo : 0.f;
        yhi = yhi > 0.f ? yhi : 0.f;
        o[4 + i] = (unsigned int)f2bf(ylo) | ((unsigned int)f2bf(yhi) << 16);
      }
      unsigned short* dst = h1 + ((size_t)b * NPAD + r0 + row) * H1 + e0;
      *(uint4*)dst = *(const uint4*)&o[0];
      *(uint4*)(dst + 8) = *(const uint4*)&o[4];
    }
  }
}

// =====================================================================
// GEMM2: 256x256 tile, BK=64, 8 waves, 8-phase counted-vmcnt schedule
// (m201 template: T2 swizzle + T3/T4 counted vmcnt + T5 setprio)
// A = h1 [51712][1024] bf16, B = W2b [512][1024] bf16 (B rows = C cols).
// Fused epilogue: bias+relu+W3 -> 2 partials/row into P (stride 4).
//
// LDS (128 KiB): buf q in {0,1}: A-half h: q*64K + h*16K; B-half h: +32K.
// Each half = 2 k-blocks [128 rows][32 shorts] (8 KiB each).  Swizzle:
// within a k-block, byte col ^= ((row&8)<<2).  global_load_lds dest is
// linear; the *source* address is pre-swizzled (rule #21).
//
// R2: snake-order quadrant visit (0,0)->(0,1)->(1,1)->(1,0) with A/B
// fragment reuse in registers -> phase reads 12/4/8/0 (was 12 each; R1
// did 2x the needed LDS reads -> LDS-BW-bound at 26% MfmaUtil).
// Stage ledger re-derived for the new read deaths (strictly-earlier
// rule, R1 lesson): deaths 0.A0@P1 0.B0@P1 0.B1@P2 0.A1@P3
// 1.A0@P5 1.B0@P5 1.B1@P6 1.A1@P7.  Prologue 7 half-tiles + vmcnt(6);
// steady vmcnt(6) at P4 lands buf1(t+1), at P8 lands buf0(t+2).
// =====================================================================
#define NT_K   16      // 1024 / 64 K-tiles
#define NITER  8       // 2 K-tiles per iteration

__global__ __launch_bounds__(512, 2) void k_gemm2x(const unsigned short* __restrict__ A,
                                                   const unsigned short* __restrict__ B,
                                                   const float* __restrict__ bias,
                                                   const float* __restrict__ W3,
                                                   float* __restrict__ P)
{
  __shared__ __align__(16) unsigned short L[65536];   // 128 KiB

  // bijective XCD swizzle (m204): nwg=404, q=50, r=4
  const int orig = blockIdx.x;
  const int xcd = orig & 7, cidx = orig >> 3;
  const int wg = (xcd < 4 ? xcd * 51 : 204 + (xcd - 4) * 50) + cidx;
  const int bm = wg >> 1, bn = wg & 1;   // bn fastest: (bm,0),(bm,1) same XCD

  const int tid  = threadIdx.x;
  const int w    = tid >> 6;
  const int lane = tid & 63;
  const int wr = w >> 2, wc = w & 3;     // 2 x 4 wave grid per quadrant
  const int arow = lane & 15;
  // swizzled col offset (shorts): colbyte (lane>>4)*16, byte bit5 ^= row bit3
  const int acol_sh = ((((lane >> 4) << 4) ^ ((arow & 8) << 2)) >> 1);

  // ---- staging source mapping (per-thread, pre-swizzled) ----
  // chunk c = tid covers LDS bytes c*16..+16 of an 8 KiB k-block;
  // source chunk c' = c ^ ((c>>5 & 1)<<1)  (same involution both sides)
  const int cs   = tid ^ (((tid >> 5) & 1) << 1);
  const size_t srcOff = ((size_t)(cs >> 2) << 10) + (size_t)((cs & 3) << 3); // row*1024 + col8*8
  const unsigned short* Ab = A + ((size_t)bm << 18) + srcOff;  // bm*256*1024
  const unsigned short* Bb = B + ((size_t)bn << 18) + srcOff;
  unsigned short* ldsw = &L[w * 512];    // wave-uniform stage base (shorts)

  // ---- ds_read per-lane bases (short units, within a buffer) ----
  const int aBase = (wr * 64 + arow) * 32 + acol_sh;           // A-half local
  const int bBase = 16384 + (wc * 32 + arow) * 32 + acol_sh;   // B region +32KiB

  f32x4 acc[2][2][4][2];
  #pragma unroll
  for (int qm = 0; qm < 2; ++qm)
    #pragma unroll
    for (int qn = 0; qn < 2; ++qn)
      #pragma unroll
      for (int i = 0; i < 4; ++i)
        #pragma unroll
        for (int j = 0; j < 2; ++j) acc[qm][qn][i][j] = (f32x4){0.f, 0.f, 0.f, 0.f};

  frag8 af[4][2];          // current A-quadrant frags (reused across 2 phases)
  frag8 bf0[2][2], bf1[2][2];  // both B-quadrant frags (qn=0 / qn=1)

// STAGE(buf, isB, half, kt): one half-tile = 2 k-blocks = 2 global_load_lds x16B
#define STAGE(buf_, isB_, half_, kt_)                                                 \
  {                                                                                   \
    const unsigned short* s_ = (isB_ ? Bb : Ab) + (size_t)(half_) * 131072 + (kt_) * 64; \
    unsigned short* d_ = ldsw + (buf_) * 32768 + (isB_) * 16384 + (half_) * 8192;     \
    async16(s_,      d_);                                                             \
    async16(s_ + 32, d_ + 4096);                                                      \
  }

#define LOAD_A(q_, qm_)                                                               \
    _Pragma("unroll")                                                                 \
    for (int ks = 0; ks < 2; ++ks)                                                    \
      _Pragma("unroll")                                                               \
      for (int i = 0; i < 4; ++i)                                                     \
        af[i][ks] = *(const frag8*)&L[(q_)*32768 + (qm_)*8192 + ks*4096 + i*512 + aBase];

#define LOAD_B(q_, qn_, bf_)                                                          \
    _Pragma("unroll")                                                                 \
    for (int ks = 0; ks < 2; ++ks)                                                    \
      _Pragma("unroll")                                                               \
      for (int j = 0; j < 2; ++j)                                                     \
        bf_[j][ks] = *(const frag8*)&L[(q_)*32768 + (qn_)*8192 + ks*4096 + j*512 + bBase];

#define MMA(qm_, qn_, bf_)                                                            \
    _Pragma("unroll")                                                                 \
    for (int ks = 0; ks < 2; ++ks)                                                    \
      _Pragma("unroll")                                                               \
      for (int i = 0; i < 4; ++i)                                                     \
        _Pragma("unroll")                                                             \
        for (int j = 0; j < 2; ++j)                                                   \
          acc[qm_][qn_][i][j] = __builtin_amdgcn_mfma_f32_16x16x32_bf16(              \
              af[i][ks], bf_[j][ks], acc[qm_][qn_][i][j], 0, 0, 0);

// one phase: {loads} {stage} barrier lgkmcnt(0) setprio MFMA setprio {vm} barrier
#define PHW(LOADS_, MMA_, STAGE_, VMW_)                                               \
  {                                                                                   \
    LOADS_                                                                            \
    STAGE_                                                                            \
    __builtin_amdgcn_sched_barrier(0);                                                \
    __builtin_amdgcn_s_barrier();                                                     \
    asm volatile("s_waitcnt lgkmcnt(0)" ::: "memory");                                \
    __builtin_amdgcn_sched_barrier(0);                                                \
    __builtin_amdgcn_s_setprio(1);                                                    \
    MMA_                                                                              \
    __builtin_amdgcn_s_setprio(0);                                                    \
    VMW_                                                                              \
    __builtin_amdgcn_s_barrier();                                                     \
    __builtin_amdgcn_sched_barrier(0);                                                \
  }

#define VM_PF()                                                                       \
  { if (pf) asm volatile("s_waitcnt vmcnt(6)" ::: "memory");                          \
    else    asm volatile("s_waitcnt vmcnt(0)" ::: "memory"); }

  // ---- prologue: buf0 all 4 halves (t0) + buf1 {A0,B0,B1} (t1) = 14 loads ----
  STAGE(0, 0, 0, 0);   // A0(t0)
  STAGE(0, 1, 0, 0);   // B0(t0)
  STAGE(0, 0, 1, 0);   // A1(t0)
  STAGE(0, 1, 1, 0);   // B1(t0)
  STAGE(1, 0, 0, 1);   // A0(t1)
  STAGE(1, 1, 0, 1);   // B0(t1)
  STAGE(1, 1, 1, 1);   // B1(t1)
  asm volatile("s_waitcnt vmcnt(6)" ::: "memory");   // tile0 (8 loads) landed
  __builtin_amdgcn_s_barrier();
  __builtin_amdgcn_sched_barrier(0);

  // ---- main loop: 8 iterations x 2 K-tiles, snake quadrant order ----
  // reads: P1{0.A0,0.B0} P2{0.B1} P3{0.A1} P4{} P5{1.A0,1.B0} P6{1.B1} P7{1.A1} P8{}
  for (int it = 0; it < NITER; ++it) {
    const int t = it * 2;
    const bool pf = (it < NITER - 1);
    PHW(LOAD_A(0,0) LOAD_B(0,0,bf0), MMA(0,0,bf0), STAGE(1,0,1,t+1);,        )  // P1: stage 1.A1<-t+1
    PHW(LOAD_B(0,1,bf1),             MMA(0,1,bf1), if(pf) STAGE(0,0,0,t+2);, )  // P2: 0.A0<-t+2
    PHW(LOAD_A(0,1),                 MMA(1,1,bf1), if(pf) STAGE(0,1,0,t+2);, )  // P3: 0.B0<-t+2
    PHW(,                            MMA(1,0,bf0), if(pf) STAGE(0,1,1,t+2);, VM_PF();)  // P4: 0.B1<-t+2
    PHW(LOAD_A(1,0) LOAD_B(1,0,bf0), MMA(0,0,bf0), if(pf) STAGE(0,0,1,t+2);, )  // P5: 0.A1<-t+2
    PHW(LOAD_B(1,1,bf1),             MMA(0,1,bf1), if(pf) STAGE(1,0,0,t+3);, )  // P6: 1.A0<-t+3
    PHW(LOAD_A(1,1),                 MMA(1,1,bf1), if(pf) STAGE(1,1,0,t+3);, )  // P7: 1.B0<-t+3
    PHW(,                            MMA(1,0,bf0), if(pf) STAGE(1,1,1,t+3);, VM_PF();)  // P8: 1.B1<-t+3
  }

  // ---- fused epilogue: bias + relu + W3 -> per-row partials over 256 cols ----
  __syncthreads();                       // fence before overlaying red on L
  float* redf = (float*)L;               // red[row_local 0..255][wc 0..3][2]

  float bj[2][2], w0v[2][2], w1v[2][2];
  #pragma unroll
  for (int qn = 0; qn < 2; ++qn)
    #pragma unroll
    for (int j = 0; j < 2; ++j) {
      const int col = bn * 256 + qn * 128 + wc * 32 + j * 16 + arow;
      bj[qn][j]  = bias[col];
      w0v[qn][j] = W3[col];
      w1v[qn][j] = W3[H2 + col];
    }
  const int g = lane >> 4;
  #pragma unroll
  for (int qm = 0; qm < 2; ++qm)
    #pragma unroll
    for (int i = 0; i < 4; ++i)
      #pragma unroll
      for (int r = 0; r < 4; ++r) {
        float s0 = 0.f, s1 = 0.f;
        #pragma unroll
        for (int qn = 0; qn < 2; ++qn)
          #pragma unroll
          for (int j = 0; j < 2; ++j) {
            float v = acc[qm][qn][i][j][r] + bj[qn][j];
            v = v > 0.f ? v : 0.f;
            s0 = fmaf(v, w0v[qn][j], s0);
            s1 = fmaf(v, w1v[qn][j], s1);
          }
        #pragma unroll
        for (int m = 1; m < 16; m <<= 1) { s0 += __shfl_xor(s0, m); s1 += __shfl_xor(s1, m); }
        if (arow == 0) {
          const int rl = qm * 128 + wr * 64 + i * 16 + g * 4 + r;
          redf[(rl * 4 + wc) * 2]     = s0;
          redf[(rl * 4 + wc) * 2 + 1] = s1;
        }
      }
  __syncthreads();
  {
    const int rl = tid >> 1, s = tid & 1;
    const float v = redf[(rl * 4 + 0) * 2 + s] + redf[(rl * 4 + 1) * 2 + s]
                  + redf[(rl * 4 + 2) * 2 + s] + redf[(rl * 4 + 3) * 2 + s];
    P[((size_t)(bm * 256 + rl)) * 4 + bn * 2 + s] = v;
  }
#undef STAGE
#undef LOAD_A
#undef LOAD_B
#undef MMA
#undef PHW
#undef VM_PF
}

// ---------------- final: sum 2 bn-partials per row -> out ----------------
__global__ __launch_bounds__(256) void k_fin(const float* __restrict__ P, float* __restrict__ out)
{
  const int row = blockIdx.x * 256 + threadIdx.x;
  if (row >= MROWS_F) return;
  const int b = row / NPAD;
  const int rr = row - b * NPAD;
  if (rr >= NCAND) return;
  const float4 pa = ((const float4*)P)[row];
  float* o = out + ((size_t)b * NCAND + rr) * 2;
  o[0] = pa.x + pa.z;
  o[1] = pa.y + pa.w;
}

// ---------------- launch ----------------
extern "C" void kernel_launch(void* const* d_in, const int* in_sizes, int n_in,
                              void* d_out, int out_size, void* d_ws, size_t ws_size,
                              hipStream_t stream)
{
  const float* doc = (const float*)d_in[0];
  const float* qe  = (const float*)d_in[1];
  const float* W1  = (const float*)d_in[2];
  const float* g1  = (const float*)d_in[3];
  const float* b1  = (const float*)d_in[4];
  const float* m1  = (const float*)d_in[5];
  const float* v1  = (const float*)d_in[6];
  const float* W2  = (const float*)d_in[7];
  const float* g2  = (const float*)d_in[8];
  const float* b2  = (const float*)d_in[9];
  const float* m2  = (const float*)d_in[10];
  const float* v2  = (const float*)d_in[11];
  const float* W3  = (const float*)d_in[12];
  float* out = (float*)d_out;

  char* ws = (char*)d_ws;
  size_t off = 0;
  auto alloc = [&](size_t bytes) -> void* {
    void* p = ws + off;
    off = (off + bytes + 255) & ~(size_t)255;
    return p;
  };
  unsigned short* Fz    = (unsigned short*)alloc((size_t)TPAD * KS * 2);
  unsigned short* Rz    = (unsigned short*)alloc((size_t)TPAD * KS * 2);
  unsigned short* Wlc   = (unsigned short*)alloc((size_t)2048 * KS * 2);
  unsigned short* Wr    = (unsigned short*)alloc((size_t)1024 * KS * 2);
  unsigned short* W2b   = (unsigned short*)alloc((size_t)H2 * H1 * 2);
  float*          bias2 = (float*)alloc((size_t)H2 * 4);
  float*          baseW = (float*)alloc((size_t)BATCH * 2048 * 4);
  unsigned short* UF    = (unsigned short*)alloc((size_t)TPAD * 2048 * 2);
  unsigned short* UR    = (unsigned short*)alloc((size_t)TPAD * 1024 * 2);
  unsigned short* h1    = (unsigned short*)alloc((size_t)MROWS_F * H1 * 2);
  float*          P     = (float*)alloc((size_t)MROWS_F * 4 * 4);
  (void)ws_size;

  // 1. fused prep (scan + qf/baseW + weight folds)
  k_prep<<<dim3(MP_TOTAL), 256, 0, stream>>>(doc, qe, W1, g1, b1, m1, v1,
                                             W2, g2, b2, m2, v2,
                                             Fz, Rz, Wlc, Wr, W2b, bias2, baseW);
  // 2. fused U-table GEMMs (base folded into UF)
  k_ugemm<<<dim3(416 + 208), 256, 0, stream>>>(Fz, Wlc, Rz, Wr, baseW, UF, UR);
  // 3. gather-combine -> h1 (bf16)
  k_combine<<<dim3(8 * 405), 512, 0, stream>>>(UF, UR, h1);
  // 4. GEMM2: 256^2 8-phase counted-vmcnt template, fused W3 partials
  k_gemm2x<<<dim3(404), 512, 0, stream>>>(h1, W2b, bias2, W3, P);
  // 5. reduce partials -> out
  k_fin<<<dim3((MROWS_F + 255) / 256), 256, 0, stream>>>(P, out);
}